// Round 17
// baseline (459.570 us; speedup 1.0000x reference)
//
#include <hip/hip_runtime.h>
#include <hip/hip_bf16.h>

typedef float f32x4 __attribute__((ext_vector_type(4)));
typedef short short8 __attribute__((ext_vector_type(8)));
typedef __bf16 bf16x8 __attribute__((ext_vector_type(8)));

#define N_TOT 16384
#define FEATS 256
#define BM 128
#define BK 32
#define KSPLIT 4
#define NSTEPS ((N_TOT / KSPLIT) / BK)   // 128
#define LDSA_BYTES (BM * 128)            // fp32 A tile, 128B rows, 16 KiB
#define LDSB_BYTES (FEATS * 64)          // bf16 B tile,  64B rows, 16 KiB
#define TILE_BYTES (LDSA_BYTES + LDSB_BYTES)

static __device__ __forceinline__ ushort f2bf(float f) {
  union { __hip_bfloat16 b; ushort u; } cv;
  cv.b = __float2bfloat16(f);
  return cv.u;
}
static __device__ __forceinline__ float bf2f(ushort u) {
  union { unsigned int i; float f; } c;
  c.i = ((unsigned int)u) << 16;
  return c.f;
}
template <int AUX>
static __device__ __forceinline__ void gload_lds16(const void* g, void* l) {
  __builtin_amdgcn_global_load_lds((const __attribute__((address_space(1))) unsigned int*)g,
                                   (__attribute__((address_space(3))) unsigned int*)l,
                                   16, 0, AUX);
}

// ---- MEASUREMENT: pure NT-read stream of the full graph (1.074 GB).
// Checksum lands in the fT region, which k_transpose fully overwrites right
// after -> final output unaffected; deterministic. t_read = total - 263us.
__global__ __launch_bounds__(256) void k_readbench(const float* __restrict__ graph,
                                                   float* __restrict__ sink) {
  const int gid = blockIdx.x * 256 + threadIdx.x;   // 2048 blocks
  const int nthr = 2048 * 256;
  const f32x4* g4 = (const f32x4*)graph;            // ext_vector: NT-builtin-legal
  float acc = 0.f;
#pragma unroll 8
  for (int k = 0; k < 128; ++k) {                   // 67,108,864 f32x4 total
    const f32x4 v = __builtin_nontemporal_load(&g4[(size_t)k * nthr + gid]);
    acc += v.x + v.y + v.z + v.w;
  }
  sink[gid] = acc;
}

// ---- K0a: transpose+convert features [16384][256] f32 -> fT [256][16384] bf16
__global__ __launch_bounds__(256) void k_transpose(const float* __restrict__ feat,
                                                   ushort* __restrict__ fT) {
  __shared__ float tile[64][65];
  const int tx = threadIdx.x & 63, ty = threadIdx.x >> 6;
  const int k0 = blockIdx.x * 64, n0 = blockIdx.y * 64;
#pragma unroll
  for (int j = 0; j < 64; j += 4)
    tile[ty + j][tx] = feat[(size_t)(k0 + ty + j) * FEATS + n0 + tx];
  __syncthreads();
#pragma unroll
  for (int j = 0; j < 64; j += 4)
    fT[(size_t)(n0 + ty + j) * N_TOT + k0 + tx] = f2bf(tile[tx][ty + j]);
}

// ---- K0b: convert W [256][256] f32 -> bf16
__global__ __launch_bounds__(256) void k_convw(const float* __restrict__ W,
                                               ushort* __restrict__ Wb) {
  int i = (blockIdx.x * 256 + threadIdx.x) * 4;
  float4 v = *(const float4*)(W + i);
  ushort4 h = { f2bf(v.x), f2bf(v.y), f2bf(v.z), f2bf(v.w) };
  *(ushort4*)(Wb + i) = h;
}

// ---- K1: r12 champion, byte-identical.
__global__ __launch_bounds__(512, 4) void k_gemm1(const float* __restrict__ graph,
                                                  const ushort* __restrict__ fT,
                                                  ushort* __restrict__ parts) {
  __shared__ char lds[2][TILE_BYTES];   // 64 KiB
  const int tid = threadIdx.x;
  const int lane = tid & 63, w = tid >> 6;
  const int wm = w >> 2, wn = w & 3;

  const int b = blockIdx.x;
  const int xcd = b & 7;
  const int kb = xcd >> 1;
  const int mi = (b >> 3) | ((xcd & 1) << 6);
  const size_t m0 = (size_t)mi * BM;
  const int kbase = kb * (N_TOT / KSPLIT);
  const int ph = (b * 53) & (NSTEPS - 1);

  auto stage = [&](int bf, int t) {
    const int k0 = kbase + t * BK;
    char* ldsA = &lds[bf][0];
    char* ldsB = &lds[bf][LDSA_BYTES];
#pragma unroll
    for (int j = 0; j < 2; ++j) {                    // A: 8 fp32 rows per instr, NT
      const int r0 = w * 16 + j * 8;
      const int row = r0 + (lane >> 3);
      const int c = (lane & 7) ^ (row & 7);
      gload_lds16<2>(graph + (m0 + row) * (size_t)N_TOT + k0 + c * 4, ldsA + r0 * 128);
    }
#pragma unroll
    for (int j = 0; j < 2; ++j) {                    // B: 16 bf16 rows per instr
      const int r0 = w * 32 + j * 16;
      const int row = r0 + (lane >> 2);
      const int c = (lane & 3) ^ (row & 3);
      gload_lds16<0>(fT + (size_t)row * N_TOT + k0 + c * 8, ldsB + r0 * 64);
    }
  };

  f32x4 acc[4][4] = {};
  const int rsel = lane & 15;
  const int kg = lane >> 4;

  auto compute = [&](int bf) {
    const char* Ab = &lds[bf][0];
    const char* Bb = &lds[bf][LDSA_BYTES];
    short8 bfr[4];
#pragma unroll
    for (int nf = 0; nf < 4; ++nf) {
      const int row = wn * 64 + nf * 16 + rsel;
      const int c = kg ^ (row & 3);
      bfr[nf] = *(const short8*)(Bb + row * 64 + c * 16);
    }
#pragma unroll
    for (int mf = 0; mf < 4; ++mf) {
      const int row = wm * 64 + mf * 16 + rsel;
      const int cb = (row & 7);
      const float4 a0 = *(const float4*)(Ab + row * 128 + ((kg * 2) ^ cb) * 16);
      const float4 a1 = *(const float4*)(Ab + row * 128 + ((kg * 2 + 1) ^ cb) * 16);
      short8 af = { (short)f2bf(a0.x), (short)f2bf(a0.y), (short)f2bf(a0.z), (short)f2bf(a0.w),
                    (short)f2bf(a1.x), (short)f2bf(a1.y), (short)f2bf(a1.z), (short)f2bf(a1.w) };
#pragma unroll
      for (int nf = 0; nf < 4; ++nf)
        acc[mf][nf] = __builtin_amdgcn_mfma_f32_16x16x32_bf16(
            __builtin_bit_cast(bf16x8, af), __builtin_bit_cast(bf16x8, bfr[nf]),
            acc[mf][nf], 0, 0, 0);
    }
  };

  stage(0, ph);
  stage(1, (ph + 1) & (NSTEPS - 1));

  for (int s = 0; s < NSTEPS - 2; ++s) {
    asm volatile("s_waitcnt vmcnt(4)" ::: "memory");
    __builtin_amdgcn_s_barrier();
    __builtin_amdgcn_sched_barrier(0);
    compute(s & 1);
    __builtin_amdgcn_s_barrier();
    stage(s & 1, (s + 2 + ph) & (NSTEPS - 1));
  }
  asm volatile("s_waitcnt vmcnt(4)" ::: "memory");
  __builtin_amdgcn_s_barrier();
  __builtin_amdgcn_sched_barrier(0);
  compute((NSTEPS - 2) & 1);
  asm volatile("s_waitcnt vmcnt(0)" ::: "memory");
  __builtin_amdgcn_s_barrier();
  __builtin_amdgcn_sched_barrier(0);
  compute((NSTEPS - 1) & 1);

  ushort* p = parts + (size_t)kb * N_TOT * FEATS;
#pragma unroll
  for (int mf = 0; mf < 4; ++mf)
#pragma unroll
    for (int nf = 0; nf < 4; ++nf)
#pragma unroll
      for (int j = 0; j < 4; ++j) {
        const int row = wm * 64 + mf * 16 + ((lane >> 4) << 2) + j;
        const int col = wn * 64 + nf * 16 + (lane & 15);
        p[(m0 + row) * FEATS + col] = f2bf(acc[mf][nf][j]);
      }
}

// ---- K2: out = relu((sum_p parts[p]) @ W^T + b), MFMA over K2=256
__global__ __launch_bounds__(256) void k_gemm2(const ushort* __restrict__ parts,
                                               const ushort* __restrict__ Wb,
                                               const float* __restrict__ bias,
                                               float* __restrict__ out) {
  __shared__ ushort Al[64][264];
  __shared__ ushort Bl[FEATS][40];
  const int tid = threadIdx.x;
  const int lane = tid & 63, w = tid >> 6;
  const size_t m0 = (size_t)blockIdx.x * 64;

  for (int c = tid; c < 2048; c += 256) {
    const int row = c >> 5;
    const int k8 = (c & 31) << 3;
    const size_t off = (m0 + row) * FEATS + k8;
    float s[8] = {0, 0, 0, 0, 0, 0, 0, 0};
#pragma unroll
    for (int p = 0; p < KSPLIT; ++p) {
      const short8 v = *(const short8*)(parts + (size_t)p * N_TOT * FEATS + off);
#pragma unroll
      for (int j = 0; j < 8; ++j) s[j] += bf2f((ushort)v[j]);
    }
    short8 ov;
#pragma unroll
    for (int j = 0; j < 8; ++j) ov[j] = (short)f2bf(s[j]);
    *(short8*)&Al[row][k8] = ov;
  }

  f32x4 acc[16] = {};
  for (int kk = 0; kk < FEATS; kk += 32) {
    __syncthreads();
#pragma unroll
    for (int q = 0; q < 4; ++q) {
      const short8 v = *(const short8*)(Wb + (size_t)tid * FEATS + kk + q * 8);
      *(short8*)&Bl[tid][q * 8] = v;
    }
    __syncthreads();
    const int koff = (lane >> 4) << 3;
    const short8 af = *(const short8*)&Al[w * 16 + (lane & 15)][kk + koff];
#pragma unroll
    for (int nf = 0; nf < 16; ++nf) {
      const short8 bfv = *(const short8*)&Bl[nf * 16 + (lane & 15)][koff];
      acc[nf] = __builtin_amdgcn_mfma_f32_16x16x32_bf16(
          __builtin_bit_cast(bf16x8, af), __builtin_bit_cast(bf16x8, bfv),
          acc[nf], 0, 0, 0);
    }
  }

#pragma unroll
  for (int nf = 0; nf < 16; ++nf) {
    const int col = nf * 16 + (lane & 15);
    const float bc = bias[col];
#pragma unroll
    for (int j = 0; j < 4; ++j) {
      const int row = w * 16 + ((lane >> 4) << 2) + j;
      const float v = acc[nf][j] + bc;
      out[(m0 + row) * FEATS + col] = fmaxf(v, 0.0f);
    }
  }
}

extern "C" void kernel_launch(void* const* d_in, const int* in_sizes, int n_in,
                              void* d_out, int out_size, void* d_ws, size_t ws_size,
                              hipStream_t stream) {
  const float* graph = (const float*)d_in[0];
  const float* feat  = (const float*)d_in[1];
  const float* W     = (const float*)d_in[2];
  const float* bias  = (const float*)d_in[3];
  float* out = (float*)d_out;

  char* ws = (char*)d_ws;
  ushort* fT    = (ushort*)ws;                                        // 8 MiB
  ushort* Wb    = (ushort*)(ws + (size_t)8 * 1024 * 1024);            // 128 KiB
  ushort* parts = (ushort*)(ws + (size_t)8 * 1024 * 1024 + 131072);   // 32 MiB

  // measurement: pure NT-read of graph; checksum into fT region (overwritten next)
  k_readbench<<<dim3(2048), 256, 0, stream>>>(graph, (float*)ws);
  k_transpose<<<dim3(N_TOT / 64, FEATS / 64), 256, 0, stream>>>(feat, fT);
  k_convw<<<dim3(64), 256, 0, stream>>>(W, Wb);
  k_gemm1<<<dim3((N_TOT / BM) * KSPLIT), 512, 0, stream>>>(graph, fT, parts);
  k_gemm2<<<dim3(N_TOT / 64), 256, 0, stream>>>(parts, Wb, bias, out);
}

// Round 18
// 328.741 us; speedup vs baseline: 1.3980x; 1.3980x over previous
//
#include <hip/hip_runtime.h>
#include <hip/hip_bf16.h>

typedef float f32x4 __attribute__((ext_vector_type(4)));
typedef short short8 __attribute__((ext_vector_type(8)));
typedef __bf16 bf16x8 __attribute__((ext_vector_type(8)));

#define N_TOT 16384
#define FEATS 256
#define BM 128
#define BK 32
#define KSPLIT 4
#define NSTEPS ((N_TOT / KSPLIT) / BK)   // 128
#define LDSA_BYTES (BM * 128)            // fp32 A tile, 128B rows, 16 KiB
#define LDSB_BYTES (FEATS * 64)          // bf16 B tile,  64B rows, 16 KiB
#define TILE_BYTES (LDSA_BYTES + LDSB_BYTES)

static __device__ __forceinline__ ushort f2bf(float f) {
  union { __hip_bfloat16 b; ushort u; } cv;
  cv.b = __float2bfloat16(f);
  return cv.u;
}
static __device__ __forceinline__ float bf2f(ushort u) {
  union { unsigned int i; float f; } c;
  c.i = ((unsigned int)u) << 16;
  return c.f;
}
template <int AUX>
static __device__ __forceinline__ void gload_lds16(const void* g, void* l) {
  __builtin_amdgcn_global_load_lds((const __attribute__((address_space(1))) unsigned int*)g,
                                   (__attribute__((address_space(3))) unsigned int*)l,
                                   16, 0, AUX);
}

// ---- K0a: transpose+convert features [16384][256] f32 -> fT [256][16384] bf16
__global__ __launch_bounds__(256) void k_transpose(const float* __restrict__ feat,
                                                   ushort* __restrict__ fT) {
  __shared__ float tile[64][65];
  const int tx = threadIdx.x & 63, ty = threadIdx.x >> 6;
  const int k0 = blockIdx.x * 64, n0 = blockIdx.y * 64;
#pragma unroll
  for (int j = 0; j < 64; j += 4)
    tile[ty + j][tx] = feat[(size_t)(k0 + ty + j) * FEATS + n0 + tx];
  __syncthreads();
#pragma unroll
  for (int j = 0; j < 64; j += 4)
    fT[(size_t)(n0 + ty + j) * N_TOT + k0 + tx] = f2bf(tile[tx][ty + j]);
}

// ---- K0b: convert W [256][256] f32 -> bf16
__global__ __launch_bounds__(256) void k_convw(const float* __restrict__ W,
                                               ushort* __restrict__ Wb) {
  int i = (blockIdx.x * 256 + threadIdx.x) * 4;
  float4 v = *(const float4*)(W + i);
  ushort4 h = { f2bf(v.x), f2bf(v.y), f2bf(v.z), f2bf(v.w) };
  *(ushort4*)(Wb + i) = h;
}

// ---- K1: r12 champion with K-INTERLEAVED KSPLIT (tile t of block kb covers
// k0=(t*4+kb)*32). The 4 sibling blocks of an m-tile read ADJACENT 128B chunks
// concurrently (ph=0, all aligned) -> 512B merged row-visits at the DRAM
// controller; B tile is chip-uniform per step -> L2-hot everywhere.
__global__ __launch_bounds__(512, 4) void k_gemm1(const float* __restrict__ graph,
                                                  const ushort* __restrict__ fT,
                                                  ushort* __restrict__ parts) {
  __shared__ char lds[2][TILE_BYTES];   // 64 KiB
  const int tid = threadIdx.x;
  const int lane = tid & 63, w = tid >> 6;
  const int wm = w >> 2, wn = w & 3;

  const int b = blockIdx.x;             // 512 blocks; b&7 = XCD (round-robin)
  const int xcd = b & 7;
  const int kb = xcd >> 1;              // interleave lane within each 512B window
  const int mi = (b >> 3) | ((xcd & 1) << 6);
  const size_t m0 = (size_t)mi * BM;

  auto stage = [&](int bf, int t) {
    const int k0 = (t * KSPLIT + kb) * BK;           // INTERLEAVED k-tile
    char* ldsA = &lds[bf][0];
    char* ldsB = &lds[bf][LDSA_BYTES];
#pragma unroll
    for (int j = 0; j < 2; ++j) {                    // A: 8 fp32 rows per instr, NT
      const int r0 = w * 16 + j * 8;
      const int row = r0 + (lane >> 3);
      const int c = (lane & 7) ^ (row & 7);
      gload_lds16<2>(graph + (m0 + row) * (size_t)N_TOT + k0 + c * 4, ldsA + r0 * 128);
    }
#pragma unroll
    for (int j = 0; j < 2; ++j) {                    // B: 16 bf16 rows per instr
      const int r0 = w * 32 + j * 16;
      const int row = r0 + (lane >> 2);
      const int c = (lane & 3) ^ (row & 3);
      gload_lds16<0>(fT + (size_t)row * N_TOT + k0 + c * 8, ldsB + r0 * 64);
    }
  };

  f32x4 acc[4][4] = {};
  const int rsel = lane & 15;
  const int kg = lane >> 4;

  auto compute = [&](int bf) {
    const char* Ab = &lds[bf][0];
    const char* Bb = &lds[bf][LDSA_BYTES];
    short8 bfr[4];
#pragma unroll
    for (int nf = 0; nf < 4; ++nf) {
      const int row = wn * 64 + nf * 16 + rsel;
      const int c = kg ^ (row & 3);
      bfr[nf] = *(const short8*)(Bb + row * 64 + c * 16);
    }
#pragma unroll
    for (int mf = 0; mf < 4; ++mf) {
      const int row = wm * 64 + mf * 16 + rsel;
      const int cb = (row & 7);
      const float4 a0 = *(const float4*)(Ab + row * 128 + ((kg * 2) ^ cb) * 16);
      const float4 a1 = *(const float4*)(Ab + row * 128 + ((kg * 2 + 1) ^ cb) * 16);
      short8 af = { (short)f2bf(a0.x), (short)f2bf(a0.y), (short)f2bf(a0.z), (short)f2bf(a0.w),
                    (short)f2bf(a1.x), (short)f2bf(a1.y), (short)f2bf(a1.z), (short)f2bf(a1.w) };
#pragma unroll
      for (int nf = 0; nf < 4; ++nf)
        acc[mf][nf] = __builtin_amdgcn_mfma_f32_16x16x32_bf16(
            __builtin_bit_cast(bf16x8, af), __builtin_bit_cast(bf16x8, bfr[nf]),
            acc[mf][nf], 0, 0, 0);
    }
  };

  stage(0, 0);
  stage(1, 1);

  for (int s = 0; s < NSTEPS - 2; ++s) {
    asm volatile("s_waitcnt vmcnt(4)" ::: "memory");
    __builtin_amdgcn_s_barrier();
    __builtin_amdgcn_sched_barrier(0);
    compute(s & 1);
    __builtin_amdgcn_s_barrier();
    stage(s & 1, s + 2);
  }
  asm volatile("s_waitcnt vmcnt(4)" ::: "memory");
  __builtin_amdgcn_s_barrier();
  __builtin_amdgcn_sched_barrier(0);
  compute((NSTEPS - 2) & 1);
  asm volatile("s_waitcnt vmcnt(0)" ::: "memory");
  __builtin_amdgcn_s_barrier();
  __builtin_amdgcn_sched_barrier(0);
  compute((NSTEPS - 1) & 1);

  // epilogue: bf16 partial store. C/D: col=lane&15, row=(lane>>4)*4+j
  ushort* p = parts + (size_t)kb * N_TOT * FEATS;
#pragma unroll
  for (int mf = 0; mf < 4; ++mf)
#pragma unroll
    for (int nf = 0; nf < 4; ++nf)
#pragma unroll
      for (int j = 0; j < 4; ++j) {
        const int row = wm * 64 + mf * 16 + ((lane >> 4) << 2) + j;
        const int col = wn * 64 + nf * 16 + (lane & 15);
        p[(m0 + row) * FEATS + col] = f2bf(acc[mf][nf][j]);
      }
}

// ---- K2: out = relu((sum_p parts[p]) @ W^T + b), MFMA over K2=256
__global__ __launch_bounds__(256) void k_gemm2(const ushort* __restrict__ parts,
                                               const ushort* __restrict__ Wb,
                                               const float* __restrict__ bias,
                                               float* __restrict__ out) {
  __shared__ ushort Al[64][264];
  __shared__ ushort Bl[FEATS][40];
  const int tid = threadIdx.x;
  const int lane = tid & 63, w = tid >> 6;
  const size_t m0 = (size_t)blockIdx.x * 64;

  for (int c = tid; c < 2048; c += 256) {
    const int row = c >> 5;
    const int k8 = (c & 31) << 3;
    const size_t off = (m0 + row) * FEATS + k8;
    float s[8] = {0, 0, 0, 0, 0, 0, 0, 0};
#pragma unroll
    for (int p = 0; p < KSPLIT; ++p) {
      const short8 v = *(const short8*)(parts + (size_t)p * N_TOT * FEATS + off);
#pragma unroll
      for (int j = 0; j < 8; ++j) s[j] += bf2f((ushort)v[j]);
    }
    short8 ov;
#pragma unroll
    for (int j = 0; j < 8; ++j) ov[j] = (short)f2bf(s[j]);
    *(short8*)&Al[row][k8] = ov;
  }

  f32x4 acc[16] = {};
  for (int kk = 0; kk < FEATS; kk += 32) {
    __syncthreads();
#pragma unroll
    for (int q = 0; q < 4; ++q) {
      const short8 v = *(const short8*)(Wb + (size_t)tid * FEATS + kk + q * 8);
      *(short8*)&Bl[tid][q * 8] = v;
    }
    __syncthreads();
    const int koff = (lane >> 4) << 3;
    const short8 af = *(const short8*)&Al[w * 16 + (lane & 15)][kk + koff];
#pragma unroll
    for (int nf = 0; nf < 16; ++nf) {
      const short8 bfv = *(const short8*)&Bl[nf * 16 + (lane & 15)][koff];
      acc[nf] = __builtin_amdgcn_mfma_f32_16x16x32_bf16(
          __builtin_bit_cast(bf16x8, af), __builtin_bit_cast(bf16x8, bfv),
          acc[nf], 0, 0, 0);
    }
  }

#pragma unroll
  for (int nf = 0; nf < 16; ++nf) {
    const int col = nf * 16 + (lane & 15);
    const float bc = bias[col];
#pragma unroll
    for (int j = 0; j < 4; ++j) {
      const int row = w * 16 + ((lane >> 4) << 2) + j;
      const float v = acc[nf][j] + bc;
      out[(m0 + row) * FEATS + col] = fmaxf(v, 0.0f);
    }
  }
}

extern "C" void kernel_launch(void* const* d_in, const int* in_sizes, int n_in,
                              void* d_out, int out_size, void* d_ws, size_t ws_size,
                              hipStream_t stream) {
  const float* graph = (const float*)d_in[0];
  const float* feat  = (const float*)d_in[1];
  const float* W     = (const float*)d_in[2];
  const float* bias  = (const float*)d_in[3];
  float* out = (float*)d_out;

  char* ws = (char*)d_ws;
  ushort* fT    = (ushort*)ws;                                        // 8 MiB
  ushort* Wb    = (ushort*)(ws + (size_t)8 * 1024 * 1024);            // 128 KiB
  ushort* parts = (ushort*)(ws + (size_t)8 * 1024 * 1024 + 131072);   // 32 MiB

  k_transpose<<<dim3(N_TOT / 64, FEATS / 64), 256, 0, stream>>>(feat, fT);
  k_convw<<<dim3(64), 256, 0, stream>>>(W, Wb);
  k_gemm1<<<dim3((N_TOT / BM) * KSPLIT), 512, 0, stream>>>(graph, fT, parts);
  k_gemm2<<<dim3(N_TOT / 64), 256, 0, stream>>>(parts, Wb, bias, out);
}

// Round 19
// 326.332 us; speedup vs baseline: 1.4083x; 1.0074x over previous
//
#include <hip/hip_runtime.h>
#include <hip/hip_bf16.h>

typedef float f32x4 __attribute__((ext_vector_type(4)));
typedef short short8 __attribute__((ext_vector_type(8)));
typedef __bf16 bf16x8 __attribute__((ext_vector_type(8)));

#define N_TOT 16384
#define FEATS 256
#define BM 128
#define BK 32
#define KSPLIT 4
#define NSTEPS ((N_TOT / KSPLIT) / BK)   // 128
#define LDSA_BYTES (BM * 128)            // fp32 A tile, 128B rows, 16 KiB
#define LDSB_BYTES (FEATS * 64)          // bf16 B tile,  64B rows, 16 KiB
#define TILE_BYTES (LDSA_BYTES + LDSB_BYTES)

static __device__ __forceinline__ ushort f2bf(float f) {
  union { __hip_bfloat16 b; ushort u; } cv;
  cv.b = __float2bfloat16(f);
  return cv.u;
}
static __device__ __forceinline__ float bf2f(ushort u) {
  union { unsigned int i; float f; } c;
  c.i = ((unsigned int)u) << 16;
  return c.f;
}
template <int AUX>
static __device__ __forceinline__ void gload_lds16(const void* g, void* l) {
  __builtin_amdgcn_global_load_lds((const __attribute__((address_space(1))) unsigned int*)g,
                                   (__attribute__((address_space(3))) unsigned int*)l,
                                   16, 0, AUX);
}

// ---- K0a: transpose+convert features [16384][256] f32 -> fT [256][16384] bf16
__global__ __launch_bounds__(256) void k_transpose(const float* __restrict__ feat,
                                                   ushort* __restrict__ fT) {
  __shared__ float tile[64][65];
  const int tx = threadIdx.x & 63, ty = threadIdx.x >> 6;
  const int k0 = blockIdx.x * 64, n0 = blockIdx.y * 64;
#pragma unroll
  for (int j = 0; j < 64; j += 4)
    tile[ty + j][tx] = feat[(size_t)(k0 + ty + j) * FEATS + n0 + tx];
  __syncthreads();
#pragma unroll
  for (int j = 0; j < 64; j += 4)
    fT[(size_t)(n0 + ty + j) * N_TOT + k0 + tx] = f2bf(tile[tx][ty + j]);
}

// ---- K0b: convert W [256][256] f32 -> bf16
__global__ __launch_bounds__(256) void k_convw(const float* __restrict__ W,
                                               ushort* __restrict__ Wb) {
  int i = (blockIdx.x * 256 + threadIdx.x) * 4;
  float4 v = *(const float4*)(W + i);
  ushort4 h = { f2bf(v.x), f2bf(v.y), f2bf(v.z), f2bf(v.w) };
  *(ushort4*)(Wb + i) = h;
}

// ---- K1: r12 champion with K-INTERLEAVED KSPLIT (tile t of block kb covers
// k0=(t*4+kb)*32). The 4 sibling blocks of an m-tile read ADJACENT 128B chunks
// concurrently (ph=0, all aligned) -> 512B merged row-visits at the DRAM
// controller; B tile is chip-uniform per step -> L2-hot everywhere.
__global__ __launch_bounds__(512, 4) void k_gemm1(const float* __restrict__ graph,
                                                  const ushort* __restrict__ fT,
                                                  ushort* __restrict__ parts) {
  __shared__ char lds[2][TILE_BYTES];   // 64 KiB
  const int tid = threadIdx.x;
  const int lane = tid & 63, w = tid >> 6;
  const int wm = w >> 2, wn = w & 3;

  const int b = blockIdx.x;             // 512 blocks; b&7 = XCD (round-robin)
  const int xcd = b & 7;
  const int kb = xcd >> 1;              // interleave lane within each 512B window
  const int mi = (b >> 3) | ((xcd & 1) << 6);
  const size_t m0 = (size_t)mi * BM;

  auto stage = [&](int bf, int t) {
    const int k0 = (t * KSPLIT + kb) * BK;           // INTERLEAVED k-tile
    char* ldsA = &lds[bf][0];
    char* ldsB = &lds[bf][LDSA_BYTES];
#pragma unroll
    for (int j = 0; j < 2; ++j) {                    // A: 8 fp32 rows per instr, NT
      const int r0 = w * 16 + j * 8;
      const int row = r0 + (lane >> 3);
      const int c = (lane & 7) ^ (row & 7);
      gload_lds16<2>(graph + (m0 + row) * (size_t)N_TOT + k0 + c * 4, ldsA + r0 * 128);
    }
#pragma unroll
    for (int j = 0; j < 2; ++j) {                    // B: 16 bf16 rows per instr
      const int r0 = w * 32 + j * 16;
      const int row = r0 + (lane >> 2);
      const int c = (lane & 3) ^ (row & 3);
      gload_lds16<0>(fT + (size_t)row * N_TOT + k0 + c * 8, ldsB + r0 * 64);
    }
  };

  f32x4 acc[4][4] = {};
  const int rsel = lane & 15;
  const int kg = lane >> 4;

  auto compute = [&](int bf) {
    const char* Ab = &lds[bf][0];
    const char* Bb = &lds[bf][LDSA_BYTES];
    short8 bfr[4];
#pragma unroll
    for (int nf = 0; nf < 4; ++nf) {
      const int row = wn * 64 + nf * 16 + rsel;
      const int c = kg ^ (row & 3);
      bfr[nf] = *(const short8*)(Bb + row * 64 + c * 16);
    }
#pragma unroll
    for (int mf = 0; mf < 4; ++mf) {
      const int row = wm * 64 + mf * 16 + rsel;
      const int cb = (row & 7);
      const float4 a0 = *(const float4*)(Ab + row * 128 + ((kg * 2) ^ cb) * 16);
      const float4 a1 = *(const float4*)(Ab + row * 128 + ((kg * 2 + 1) ^ cb) * 16);
      short8 af = { (short)f2bf(a0.x), (short)f2bf(a0.y), (short)f2bf(a0.z), (short)f2bf(a0.w),
                    (short)f2bf(a1.x), (short)f2bf(a1.y), (short)f2bf(a1.z), (short)f2bf(a1.w) };
#pragma unroll
      for (int nf = 0; nf < 4; ++nf)
        acc[mf][nf] = __builtin_amdgcn_mfma_f32_16x16x32_bf16(
            __builtin_bit_cast(bf16x8, af), __builtin_bit_cast(bf16x8, bfr[nf]),
            acc[mf][nf], 0, 0, 0);
    }
  };

  stage(0, 0);
  stage(1, 1);

  for (int s = 0; s < NSTEPS - 2; ++s) {
    asm volatile("s_waitcnt vmcnt(4)" ::: "memory");
    __builtin_amdgcn_s_barrier();
    __builtin_amdgcn_sched_barrier(0);
    compute(s & 1);
    __builtin_amdgcn_s_barrier();
    stage(s & 1, s + 2);
  }
  asm volatile("s_waitcnt vmcnt(4)" ::: "memory");
  __builtin_amdgcn_s_barrier();
  __builtin_amdgcn_sched_barrier(0);
  compute((NSTEPS - 2) & 1);
  asm volatile("s_waitcnt vmcnt(0)" ::: "memory");
  __builtin_amdgcn_s_barrier();
  __builtin_amdgcn_sched_barrier(0);
  compute((NSTEPS - 1) & 1);

  // epilogue: bf16 partial store. C/D: col=lane&15, row=(lane>>4)*4+j
  ushort* p = parts + (size_t)kb * N_TOT * FEATS;
#pragma unroll
  for (int mf = 0; mf < 4; ++mf)
#pragma unroll
    for (int nf = 0; nf < 4; ++nf)
#pragma unroll
      for (int j = 0; j < 4; ++j) {
        const int row = wm * 64 + mf * 16 + ((lane >> 4) << 2) + j;
        const int col = wn * 64 + nf * 16 + (lane & 15);
        p[(m0 + row) * FEATS + col] = f2bf(acc[mf][nf][j]);
      }
}

// ---- K2: out = relu((sum_p parts[p]) @ W^T + b), MFMA over K2=256
__global__ __launch_bounds__(256) void k_gemm2(const ushort* __restrict__ parts,
                                               const ushort* __restrict__ Wb,
                                               const float* __restrict__ bias,
                                               float* __restrict__ out) {
  __shared__ ushort Al[64][264];
  __shared__ ushort Bl[FEATS][40];
  const int tid = threadIdx.x;
  const int lane = tid & 63, w = tid >> 6;
  const size_t m0 = (size_t)blockIdx.x * 64;

  for (int c = tid; c < 2048; c += 256) {
    const int row = c >> 5;
    const int k8 = (c & 31) << 3;
    const size_t off = (m0 + row) * FEATS + k8;
    float s[8] = {0, 0, 0, 0, 0, 0, 0, 0};
#pragma unroll
    for (int p = 0; p < KSPLIT; ++p) {
      const short8 v = *(const short8*)(parts + (size_t)p * N_TOT * FEATS + off);
#pragma unroll
      for (int j = 0; j < 8; ++j) s[j] += bf2f((ushort)v[j]);
    }
    short8 ov;
#pragma unroll
    for (int j = 0; j < 8; ++j) ov[j] = (short)f2bf(s[j]);
    *(short8*)&Al[row][k8] = ov;
  }

  f32x4 acc[16] = {};
  for (int kk = 0; kk < FEATS; kk += 32) {
    __syncthreads();
#pragma unroll
    for (int q = 0; q < 4; ++q) {
      const short8 v = *(const short8*)(Wb + (size_t)tid * FEATS + kk + q * 8);
      *(short8*)&Bl[tid][q * 8] = v;
    }
    __syncthreads();
    const int koff = (lane >> 4) << 3;
    const short8 af = *(const short8*)&Al[w * 16 + (lane & 15)][kk + koff];
#pragma unroll
    for (int nf = 0; nf < 16; ++nf) {
      const short8 bfv = *(const short8*)&Bl[nf * 16 + (lane & 15)][koff];
      acc[nf] = __builtin_amdgcn_mfma_f32_16x16x32_bf16(
          __builtin_bit_cast(bf16x8, af), __builtin_bit_cast(bf16x8, bfv),
          acc[nf], 0, 0, 0);
    }
  }

#pragma unroll
  for (int nf = 0; nf < 16; ++nf) {
    const int col = nf * 16 + (lane & 15);
    const float bc = bias[col];
#pragma unroll
    for (int j = 0; j < 4; ++j) {
      const int row = w * 16 + ((lane >> 4) << 2) + j;
      const float v = acc[nf][j] + bc;
      out[(m0 + row) * FEATS + col] = fmaxf(v, 0.0f);
    }
  }
}

extern "C" void kernel_launch(void* const* d_in, const int* in_sizes, int n_in,
                              void* d_out, int out_size, void* d_ws, size_t ws_size,
                              hipStream_t stream) {
  const float* graph = (const float*)d_in[0];
  const float* feat  = (const float*)d_in[1];
  const float* W     = (const float*)d_in[2];
  const float* bias  = (const float*)d_in[3];
  float* out = (float*)d_out;

  char* ws = (char*)d_ws;
  ushort* fT    = (ushort*)ws;                                        // 8 MiB
  ushort* Wb    = (ushort*)(ws + (size_t)8 * 1024 * 1024);            // 128 KiB
  ushort* parts = (ushort*)(ws + (size_t)8 * 1024 * 1024 + 131072);   // 32 MiB

  k_transpose<<<dim3(N_TOT / 64, FEATS / 64), 256, 0, stream>>>(feat, fT);
  k_convw<<<dim3(64), 256, 0, stream>>>(W, Wb);
  k_gemm1<<<dim3((N_TOT / BM) * KSPLIT), 512, 0, stream>>>(graph, fT, parts);
  k_gemm2<<<dim3(N_TOT / 64), 256, 0, stream>>>(parts, Wb, bias, out);
}

// Round 20
// 261.840 us; speedup vs baseline: 1.7552x; 1.2463x over previous
//
#include <hip/hip_runtime.h>
#include <hip/hip_bf16.h>

typedef float f32x4 __attribute__((ext_vector_type(4)));
typedef short short8 __attribute__((ext_vector_type(8)));
typedef __bf16 bf16x8 __attribute__((ext_vector_type(8)));

#define N_TOT 16384
#define FEATS 256
#define BM 128
#define BK 32
#define KSPLIT 4
#define NSTEPS ((N_TOT / KSPLIT) / BK)   // 128
#define LDSA_BYTES (BM * 128)            // fp32 A tile, 128B rows, 16 KiB
#define LDSB_BYTES (FEATS * 64)          // bf16 B tile,  64B rows, 16 KiB
#define TILE_BYTES (LDSA_BYTES + LDSB_BYTES)

static __device__ __forceinline__ ushort f2bf(float f) {
  union { __hip_bfloat16 b; ushort u; } cv;
  cv.b = __float2bfloat16(f);
  return cv.u;
}
static __device__ __forceinline__ float bf2f(ushort u) {
  union { unsigned int i; float f; } c;
  c.i = ((unsigned int)u) << 16;
  return c.f;
}
// aux CPol: bit1 = NT. A-stream NT=2 (zero reuse -> skip L2 alloc; r12: -7%).
template <int AUX>
static __device__ __forceinline__ void gload_lds16(const void* g, void* l) {
  __builtin_amdgcn_global_load_lds((const __attribute__((address_space(1))) unsigned int*)g,
                                   (__attribute__((address_space(3))) unsigned int*)l,
                                   16, 0, AUX);
}

// ---- K0a: transpose+convert features [16384][256] f32 -> fT [256][16384] bf16
__global__ __launch_bounds__(256) void k_transpose(const float* __restrict__ feat,
                                                   ushort* __restrict__ fT) {
  __shared__ float tile[64][65];
  const int tx = threadIdx.x & 63, ty = threadIdx.x >> 6;
  const int k0 = blockIdx.x * 64, n0 = blockIdx.y * 64;
#pragma unroll
  for (int j = 0; j < 64; j += 4)
    tile[ty + j][tx] = feat[(size_t)(k0 + ty + j) * FEATS + n0 + tx];
  __syncthreads();
#pragma unroll
  for (int j = 0; j < 64; j += 4)
    fT[(size_t)(n0 + ty + j) * N_TOT + k0 + tx] = f2bf(tile[tx][ty + j]);
}

// ---- K0b: convert W [256][256] f32 -> bf16
__global__ __launch_bounds__(256) void k_convw(const float* __restrict__ W,
                                               ushort* __restrict__ Wb) {
  int i = (blockIdx.x * 256 + threadIdx.x) * 4;
  float4 v = *(const float4*)(W + i);
  ushort4 h = { f2bf(v.x), f2bf(v.y), f2bf(v.z), f2bf(v.w) };
  *(ushort4*)(Wb + i) = h;
}

// ---- K1: champion (r12, 263us). BM=128, BK=32, KSPLIT=4 contiguous quarters,
// depth-2 glds pipeline, counted vmcnt(4) (never drained in-loop), NT on the
// A-stream, XOR-involution pre-swizzled sources, de-phased k-start per block.
__global__ __launch_bounds__(512, 4) void k_gemm1(const float* __restrict__ graph,
                                                  const ushort* __restrict__ fT,
                                                  ushort* __restrict__ parts) {
  __shared__ char lds[2][TILE_BYTES];   // 64 KiB -> 2 blocks/CU
  const int tid = threadIdx.x;
  const int lane = tid & 63, w = tid >> 6;
  const int wm = w >> 2, wn = w & 3;

  const int b = blockIdx.x;             // 512 blocks; b&7 = XCD (round-robin)
  const int xcd = b & 7;
  const int kb = xcd >> 1;              // kb chunk pinned to an XCD pair
  const int mi = (b >> 3) | ((xcd & 1) << 6);
  const size_t m0 = (size_t)mi * BM;
  const int kbase = kb * (N_TOT / KSPLIT);
  const int ph = (b * 53) & (NSTEPS - 1);   // per-block k-phase rotation

  auto stage = [&](int bf, int t) {
    const int k0 = kbase + t * BK;
    char* ldsA = &lds[bf][0];
    char* ldsB = &lds[bf][LDSA_BYTES];
#pragma unroll
    for (int j = 0; j < 2; ++j) {                    // A: 8 fp32 rows per instr, NT
      const int r0 = w * 16 + j * 8;
      const int row = r0 + (lane >> 3);
      const int c = (lane & 7) ^ (row & 7);
      gload_lds16<2>(graph + (m0 + row) * (size_t)N_TOT + k0 + c * 4, ldsA + r0 * 128);
    }
#pragma unroll
    for (int j = 0; j < 2; ++j) {                    // B: 16 bf16 rows per instr
      const int r0 = w * 32 + j * 16;
      const int row = r0 + (lane >> 2);
      const int c = (lane & 3) ^ (row & 3);
      gload_lds16<0>(fT + (size_t)row * N_TOT + k0 + c * 8, ldsB + r0 * 64);
    }
  };

  f32x4 acc[4][4] = {};
  const int rsel = lane & 15;
  const int kg = lane >> 4;

  auto compute = [&](int bf) {
    const char* Ab = &lds[bf][0];
    const char* Bb = &lds[bf][LDSA_BYTES];
    short8 bfr[4];
#pragma unroll
    for (int nf = 0; nf < 4; ++nf) {
      const int row = wn * 64 + nf * 16 + rsel;
      const int c = kg ^ (row & 3);
      bfr[nf] = *(const short8*)(Bb + row * 64 + c * 16);
    }
#pragma unroll
    for (int mf = 0; mf < 4; ++mf) {
      const int row = wm * 64 + mf * 16 + rsel;
      const int cb = (row & 7);
      const float4 a0 = *(const float4*)(Ab + row * 128 + ((kg * 2) ^ cb) * 16);
      const float4 a1 = *(const float4*)(Ab + row * 128 + ((kg * 2 + 1) ^ cb) * 16);
      short8 af = { (short)f2bf(a0.x), (short)f2bf(a0.y), (short)f2bf(a0.z), (short)f2bf(a0.w),
                    (short)f2bf(a1.x), (short)f2bf(a1.y), (short)f2bf(a1.z), (short)f2bf(a1.w) };
#pragma unroll
      for (int nf = 0; nf < 4; ++nf)
        acc[mf][nf] = __builtin_amdgcn_mfma_f32_16x16x32_bf16(
            __builtin_bit_cast(bf16x8, af), __builtin_bit_cast(bf16x8, bfr[nf]),
            acc[mf][nf], 0, 0, 0);
    }
  };

  stage(0, ph);
  stage(1, (ph + 1) & (NSTEPS - 1));

  for (int s = 0; s < NSTEPS - 2; ++s) {
    asm volatile("s_waitcnt vmcnt(4)" ::: "memory");
    __builtin_amdgcn_s_barrier();
    __builtin_amdgcn_sched_barrier(0);
    compute(s & 1);
    __builtin_amdgcn_s_barrier();
    stage(s & 1, (s + 2 + ph) & (NSTEPS - 1));
  }
  asm volatile("s_waitcnt vmcnt(4)" ::: "memory");
  __builtin_amdgcn_s_barrier();
  __builtin_amdgcn_sched_barrier(0);
  compute((NSTEPS - 2) & 1);
  asm volatile("s_waitcnt vmcnt(0)" ::: "memory");
  __builtin_amdgcn_s_barrier();
  __builtin_amdgcn_sched_barrier(0);
  compute((NSTEPS - 1) & 1);

  // epilogue: bf16 partial store. C/D: col=lane&15, row=(lane>>4)*4+j
  ushort* p = parts + (size_t)kb * N_TOT * FEATS;
#pragma unroll
  for (int mf = 0; mf < 4; ++mf)
#pragma unroll
    for (int nf = 0; nf < 4; ++nf)
#pragma unroll
      for (int j = 0; j < 4; ++j) {
        const int row = wm * 64 + mf * 16 + ((lane >> 4) << 2) + j;
        const int col = wn * 64 + nf * 16 + (lane & 15);
        p[(m0 + row) * FEATS + col] = f2bf(acc[mf][nf][j]);
      }
}

// ---- K2: out = relu((sum_p parts[p]) @ W^T + b), MFMA over K2=256
__global__ __launch_bounds__(256) void k_gemm2(const ushort* __restrict__ parts,
                                               const ushort* __restrict__ Wb,
                                               const float* __restrict__ bias,
                                               float* __restrict__ out) {
  __shared__ ushort Al[64][264];
  __shared__ ushort Bl[FEATS][40];
  const int tid = threadIdx.x;
  const int lane = tid & 63, w = tid >> 6;
  const size_t m0 = (size_t)blockIdx.x * 64;

  for (int c = tid; c < 2048; c += 256) {
    const int row = c >> 5;
    const int k8 = (c & 31) << 3;
    const size_t off = (m0 + row) * FEATS + k8;
    float s[8] = {0, 0, 0, 0, 0, 0, 0, 0};
#pragma unroll
    for (int p = 0; p < KSPLIT; ++p) {
      const short8 v = *(const short8*)(parts + (size_t)p * N_TOT * FEATS + off);
#pragma unroll
      for (int j = 0; j < 8; ++j) s[j] += bf2f((ushort)v[j]);
    }
    short8 ov;
#pragma unroll
    for (int j = 0; j < 8; ++j) ov[j] = (short)f2bf(s[j]);
    *(short8*)&Al[row][k8] = ov;
  }

  f32x4 acc[16] = {};
  for (int kk = 0; kk < FEATS; kk += 32) {
    __syncthreads();
#pragma unroll
    for (int q = 0; q < 4; ++q) {
      const short8 v = *(const short8*)(Wb + (size_t)tid * FEATS + kk + q * 8);
      *(short8*)&Bl[tid][q * 8] = v;
    }
    __syncthreads();
    const int koff = (lane >> 4) << 3;
    const short8 af = *(const short8*)&Al[w * 16 + (lane & 15)][kk + koff];
#pragma unroll
    for (int nf = 0; nf < 16; ++nf) {
      const short8 bfv = *(const short8*)&Bl[nf * 16 + (lane & 15)][koff];
      acc[nf] = __builtin_amdgcn_mfma_f32_16x16x32_bf16(
          __builtin_bit_cast(bf16x8, af), __builtin_bit_cast(bf16x8, bfv),
          acc[nf], 0, 0, 0);
    }
  }

#pragma unroll
  for (int nf = 0; nf < 16; ++nf) {
    const int col = nf * 16 + (lane & 15);
    const float bc = bias[col];
#pragma unroll
    for (int j = 0; j < 4; ++j) {
      const int row = w * 16 + ((lane >> 4) << 2) + j;
      const float v = acc[nf][j] + bc;
      out[(m0 + row) * FEATS + col] = fmaxf(v, 0.0f);
    }
  }
}

extern "C" void kernel_launch(void* const* d_in, const int* in_sizes, int n_in,
                              void* d_out, int out_size, void* d_ws, size_t ws_size,
                              hipStream_t stream) {
  const float* graph = (const float*)d_in[0];
  const float* feat  = (const float*)d_in[1];
  const float* W     = (const float*)d_in[2];
  const float* bias  = (const float*)d_in[3];
  float* out = (float*)d_out;

  char* ws = (char*)d_ws;
  ushort* fT    = (ushort*)ws;                                        // 8 MiB
  ushort* Wb    = (ushort*)(ws + (size_t)8 * 1024 * 1024);            // 128 KiB
  ushort* parts = (ushort*)(ws + (size_t)8 * 1024 * 1024 + 131072);   // 32 MiB

  k_transpose<<<dim3(N_TOT / 64, FEATS / 64), 256, 0, stream>>>(feat, fT);
  k_convw<<<dim3(64), 256, 0, stream>>>(W, Wb);
  k_gemm1<<<dim3((N_TOT / BM) * KSPLIT), 512, 0, stream>>>(graph, fT, parts);
  k_gemm2<<<dim3(N_TOT / 64), 256, 0, stream>>>(parts, Wb, bias, out);
}